// Round 4
// baseline (56.866 us; speedup 1.0000x reference)
//
#include <hip/hip_runtime.h>
#include <hip/hip_fp16.h>

#define B_ 2
#define C_ 32
#define H_ 256
#define W_ 256
#define K_ 4
#define HW_ (H_ * W_)

// ---------------------------------------------------------------------------
// Transpose+convert v (B,C,H,W) fp32 -> vt (B,H*W,C) fp16.
// Each pixel's 32 channels = one contiguous 64B segment (one cache line).
// v reads are nontemporal (no reuse); vt stores stream via uint bit-cast
// (nontemporal builtin rejects __half2*).
// ---------------------------------------------------------------------------
__global__ __launch_bounds__(256) void transpose_v_kernel(
    const float* __restrict__ v, unsigned int* __restrict__ vt) {
  __shared__ float tile[32][65];  // +1 pad: conflict-free transpose reads
  int t = threadIdx.x;
  int pix0 = blockIdx.x * 64;          // global pixel index in [0, B*HW)
  int b = pix0 >> 16;                  // / HW_
  int pixb = pix0 & (HW_ - 1);
  const float* vb = v + (size_t)b * C_ * HW_;
#pragma unroll
  for (int it = 0; it < 8; ++it) {
    int c = (t >> 6) + it * 4;
    int px = t & 63;
    tile[c][px] = __builtin_nontemporal_load(&vb[(size_t)c * HW_ + pixb + px]);
  }
  __syncthreads();
  unsigned int* vtb = vt + (size_t)pix0 * (C_ / 2);
#pragma unroll
  for (int it = 0; it < 4; ++it) {
    int px = (t >> 4) + it * 16;
    int c2 = t & 15;
    float lo = tile[2 * c2][px];
    float hi = tile[2 * c2 + 1][px];
    __half2 h = __floats2half2_rn(lo, hi);
    unsigned int bits;
    __builtin_memcpy(&bits, &h, 4);
    __builtin_nontemporal_store(bits, &vtb[px * 16 + c2]);  // 64B/px coalesced
  }
}

// ---------------------------------------------------------------------------
// Main kernel. One 256-thread block per 64 consecutive x of one row y.
// Block->work mapping is XCD-batch-partitioned: XCDs 0-3 own batch 0,
// XCDs 4-7 own batch 1, so each XCD's gather set (vt[b] = 4 MiB fp16)
// fits its 4 MiB L2. Streaming traffic (cost/shift in, out stores) is
// nontemporal so it doesn't evict vt.
// ---------------------------------------------------------------------------
__global__ __launch_bounds__(256, 4) void psatt_kernel(
    const float* __restrict__ cost_map, const int* __restrict__ shift_map,
    const __half2* __restrict__ vt, float* __restrict__ out) {
  __shared__ float lds_e[64][37];    // stride 37: conflict-free ph1 writes
  __shared__ int lds_off[64][37];
  __shared__ float lds_part[64][4];
  __shared__ float lds_inv[64];
  __shared__ float lds_out[64][33];  // stride 33: conflict-free epilogue reads

  int t = threadIdx.x;
  // XCD-aware decomposition (empirical round-robin: XCD = blockIdx % 8).
  int bid = blockIdx.x;           // 0..2047
  int xcd = bid & 7;
  int slot = bid >> 3;            // 0..255
  int b = xcd >> 2;               // XCDs 0-3 -> batch 0, 4-7 -> batch 1
  int workid = ((xcd & 3) << 8) + slot;  // 0..1023; 64 contiguous rows/XCD
  int y = workid >> 2;
  int x0 = (workid & 3) << 6;

  // ---- phase 1: weights + offsets -----------------------------------------
  {
    int k = t >> 6;   // one wave per k-plane
    int px = t & 63;
    int x = x0 + px;
    const float* cm = cost_map + (size_t)(b * K_ + k) * HW_;
    const int* s0 = shift_map + (size_t)((b * 2 + 0) * K_ + k) * HW_;
    const int* s1 = shift_map + (size_t)((b * 2 + 1) * K_ + k) * HW_;
    float psum = 0.f;
#pragma unroll
    for (int di = 0; di < 3; ++di) {
      int ny = y + di - 1;
      bool yin = (unsigned)ny < (unsigned)H_;
#pragma unroll
      for (int dj = 0; dj < 3; ++dj) {
        int nx = x + dj - 1;
        bool inb = yin && ((unsigned)nx < (unsigned)W_);
        int nidx = ny * W_ + nx;
        float cost;
        int si, sj;
        if (inb) {
          cost = __builtin_nontemporal_load(&cm[nidx]);
          si = __builtin_nontemporal_load(&s0[nidx]) + (1 - di);
          sj = __builtin_nontemporal_load(&s1[nidx]) + (1 - dj);
        } else {
          cost = 10.0f;     // pad value of cost_map
          si = 11 - di;     // pad value 10 + (1 - di)
          sj = 11 - dj;
        }
        float e = __expf(-cost);  // T = 1; no max-sub needed (range safe)
        int ii = min(max(si, 0), H_ - 1);
        int jj = min(max(sj, 0), W_ - 1);
        int m = k * 9 + di * 3 + dj;
        lds_e[px][m] = e;
        lds_off[px][m] = ii * W_ + jj;
        psum += e;
      }
    }
    lds_part[px][k] = psum;
  }
  __syncthreads();
  if (t < 64) {
    lds_inv[t] =
        1.0f / (lds_part[t][0] + lds_part[t][1] + lds_part[t][2] + lds_part[t][3]);
  }
  __syncthreads();

  // ---- phase 2: weighted gather-sum (fp16 vt, 4 px in flight) -------------
  {
    int g = t >> 4;    // 16 groups of 16 lanes
    int c2 = t & 15;   // channel pair: channels 2*c2, 2*c2+1
    const __half2* vb = vt + (size_t)b * HW_ * 16 + c2;
    int px0 = g << 2;
    float a0x = 0.f, a0y = 0.f, a1x = 0.f, a1y = 0.f;
    float a2x = 0.f, a2y = 0.f, a3x = 0.f, a3y = 0.f;
#pragma unroll 9
    for (int m = 0; m < 36; ++m) {
      int o0 = lds_off[px0 + 0][m];   // broadcast LDS reads (16-lane groups)
      int o1 = lds_off[px0 + 1][m];
      int o2 = lds_off[px0 + 2][m];
      int o3 = lds_off[px0 + 3][m];
      float e0 = lds_e[px0 + 0][m];
      float e1 = lds_e[px0 + 1][m];
      float e2 = lds_e[px0 + 2][m];
      float e3 = lds_e[px0 + 3][m];
      float2 f0 = __half22float2(vb[(size_t)o0 << 4]);
      float2 f1 = __half22float2(vb[(size_t)o1 << 4]);
      float2 f2 = __half22float2(vb[(size_t)o2 << 4]);
      float2 f3 = __half22float2(vb[(size_t)o3 << 4]);
      a0x += e0 * f0.x; a0y += e0 * f0.y;
      a1x += e1 * f1.x; a1y += e1 * f1.y;
      a2x += e2 * f2.x; a2y += e2 * f2.y;
      a3x += e3 * f3.x; a3y += e3 * f3.y;
    }
    float i0 = lds_inv[px0 + 0], i1 = lds_inv[px0 + 1];
    float i2 = lds_inv[px0 + 2], i3 = lds_inv[px0 + 3];
    lds_out[px0 + 0][2 * c2] = a0x * i0; lds_out[px0 + 0][2 * c2 + 1] = a0y * i0;
    lds_out[px0 + 1][2 * c2] = a1x * i1; lds_out[px0 + 1][2 * c2 + 1] = a1y * i1;
    lds_out[px0 + 2][2 * c2] = a2x * i2; lds_out[px0 + 2][2 * c2 + 1] = a2y * i2;
    lds_out[px0 + 3][2 * c2] = a3x * i3; lds_out[px0 + 3][2 * c2 + 1] = a3y * i3;
  }
  __syncthreads();

  // ---- epilogue: transpose to channel-major, nontemporal coalesced stores -
  {
    int px = t & 63;
#pragma unroll
    for (int it = 0; it < 8; ++it) {
      int c = (t >> 6) + it * 4;
      __builtin_nontemporal_store(
          lds_out[px][c],
          &out[((size_t)(b * C_ + c) * H_ + y) * W_ + x0 + px]);
    }
  }
}

extern "C" void kernel_launch(void* const* d_in, const int* in_sizes, int n_in,
                              void* d_out, int out_size, void* d_ws, size_t ws_size,
                              hipStream_t stream) {
  const float* v = (const float*)d_in[0];
  const float* cost_map = (const float*)d_in[1];
  const int* shift_map = (const int*)d_in[2];
  float* out = (float*)d_out;

  unsigned int* vt = (unsigned int*)d_ws;  // B*HW*16 uints = 8.4 MB
  const int grid = B_ * H_ * (W_ / 64);    // 2048 blocks

  transpose_v_kernel<<<B_ * HW_ / 64, 256, 0, stream>>>(v, vt);
  psatt_kernel<<<grid, 256, 0, stream>>>(cost_map, shift_map,
                                         (const __half2*)vt, out);
}

// Round 5
// 53.300 us; speedup vs baseline: 1.0669x; 1.0669x over previous
//
#include <hip/hip_runtime.h>
#include <hip/hip_fp16.h>

#define B_ 2
#define C_ 32
#define H_ 256
#define W_ 256
#define K_ 4
#define HW_ (H_ * W_)

// ---------------------------------------------------------------------------
// Transpose+convert v (B,C,H,W) fp32 -> vt (B,H*W,C) fp16.
// Each pixel's 32 channels = one contiguous 64B segment (one cache line).
// v reads are nontemporal (single touch); vt stores via uint bit-cast.
// ---------------------------------------------------------------------------
__global__ __launch_bounds__(256) void transpose_v_kernel(
    const float* __restrict__ v, unsigned int* __restrict__ vt) {
  __shared__ float tile[32][65];  // +1 pad: conflict-free transpose reads
  int t = threadIdx.x;
  int pix0 = blockIdx.x * 64;          // global pixel index in [0, B*HW)
  int b = pix0 >> 16;                  // / HW_
  int pixb = pix0 & (HW_ - 1);
  const float* vb = v + (size_t)b * C_ * HW_;
#pragma unroll
  for (int it = 0; it < 8; ++it) {
    int c = (t >> 6) + it * 4;
    int px = t & 63;
    tile[c][px] = __builtin_nontemporal_load(&vb[(size_t)c * HW_ + pixb + px]);
  }
  __syncthreads();
  unsigned int* vtb = vt + (size_t)pix0 * (C_ / 2);
#pragma unroll
  for (int it = 0; it < 4; ++it) {
    int px = (t >> 4) + it * 16;
    int c2 = t & 15;
    float lo = tile[2 * c2][px];
    float hi = tile[2 * c2 + 1][px];
    __half2 h = __floats2half2_rn(lo, hi);
    unsigned int bits;
    __builtin_memcpy(&bits, &h, 4);
    __builtin_nontemporal_store(bits, &vtb[px * 16 + c2]);  // 64B/px coalesced
  }
}

// ---------------------------------------------------------------------------
// Main kernel. One 256-thread block per 64 consecutive x of one row y.
// XCD-batch partition (confirmed R4: FETCH 100->25MB): XCDs 0-3 own batch 0,
// XCDs 4-7 batch 1, so each XCD's gather set (vt[b] = 4 MiB) fits its L2.
// Phase 2 issues gathers in explicit 48-load batches (12 taps x 4 px) to get
// deep MLP over ~200-cycle L2 hit latency (R4 regression: compiler kept only
// ~8 in flight).
// ---------------------------------------------------------------------------
__global__ __launch_bounds__(256, 4) void psatt_kernel(
    const float* __restrict__ cost_map, const int* __restrict__ shift_map,
    const __half2* __restrict__ vt, float* __restrict__ out) {
  __shared__ float lds_e[64][37];    // stride 37: conflict-free ph1 writes
  __shared__ int lds_off[64][37];
  __shared__ float lds_part[64][4];
  __shared__ float lds_inv[64];
  __shared__ float lds_out[64][33];  // stride 33: conflict-free epilogue reads

  int t = threadIdx.x;
  // XCD-aware decomposition (empirical round-robin: XCD = blockIdx % 8).
  int bid = blockIdx.x;           // 0..2047
  int xcd = bid & 7;
  int slot = bid >> 3;            // 0..255
  int b = xcd >> 2;               // XCDs 0-3 -> batch 0, 4-7 -> batch 1
  int workid = ((xcd & 3) << 8) + slot;  // 0..1023; 64 contiguous rows/XCD
  int y = workid >> 2;
  int x0 = (workid & 3) << 6;

  // ---- phase 1: weights + offsets (plain loads: halo rows L2-reused) ------
  {
    int k = t >> 6;   // one wave per k-plane
    int px = t & 63;
    int x = x0 + px;
    const float* cm = cost_map + (size_t)(b * K_ + k) * HW_;
    const int* s0 = shift_map + (size_t)((b * 2 + 0) * K_ + k) * HW_;
    const int* s1 = shift_map + (size_t)((b * 2 + 1) * K_ + k) * HW_;
    float psum = 0.f;
#pragma unroll
    for (int di = 0; di < 3; ++di) {
      int ny = y + di - 1;
      bool yin = (unsigned)ny < (unsigned)H_;
#pragma unroll
      for (int dj = 0; dj < 3; ++dj) {
        int nx = x + dj - 1;
        bool inb = yin && ((unsigned)nx < (unsigned)W_);
        int nidx = ny * W_ + nx;
        float cost;
        int si, sj;
        if (inb) {
          cost = cm[nidx];
          si = s0[nidx] + (1 - di);
          sj = s1[nidx] + (1 - dj);
        } else {
          cost = 10.0f;     // pad value of cost_map
          si = 11 - di;     // pad value 10 + (1 - di)
          sj = 11 - dj;
        }
        float e = __expf(-cost);  // T = 1; no max-sub needed (range safe)
        int ii = min(max(si, 0), H_ - 1);
        int jj = min(max(sj, 0), W_ - 1);
        int m = k * 9 + di * 3 + dj;
        lds_e[px][m] = e;
        lds_off[px][m] = ii * W_ + jj;
        psum += e;
      }
    }
    lds_part[px][k] = psum;
  }
  __syncthreads();
  if (t < 64) {
    lds_inv[t] =
        1.0f / (lds_part[t][0] + lds_part[t][1] + lds_part[t][2] + lds_part[t][3]);
  }
  __syncthreads();

  // ---- phase 2: weighted gather-sum, explicit 48-load batches -------------
  {
    int g = t >> 4;    // 16 groups of 16 lanes
    int c2 = t & 15;   // channel pair: channels 2*c2, 2*c2+1
    const __half2* vb = vt + (size_t)b * HW_ * 16 + c2;
    int px0 = g << 2;
    float accx[4] = {0.f, 0.f, 0.f, 0.f};
    float accy[4] = {0.f, 0.f, 0.f, 0.f};
#pragma unroll
    for (int base = 0; base < 36; base += 12) {
      __half2 hv[12][4];  // fully static-indexed after unroll -> VGPRs
#pragma unroll
      for (int m = 0; m < 12; ++m) {
#pragma unroll
        for (int p = 0; p < 4; ++p) {
          hv[m][p] = vb[(size_t)lds_off[px0 + p][base + m] << 4];
        }
      }
#pragma unroll
      for (int m = 0; m < 12; ++m) {
#pragma unroll
        for (int p = 0; p < 4; ++p) {
          float e = lds_e[px0 + p][base + m];
          float2 f = __half22float2(hv[m][p]);
          accx[p] += e * f.x;
          accy[p] += e * f.y;
        }
      }
    }
#pragma unroll
    for (int p = 0; p < 4; ++p) {
      float inv = lds_inv[px0 + p];
      lds_out[px0 + p][2 * c2]     = accx[p] * inv;
      lds_out[px0 + p][2 * c2 + 1] = accy[p] * inv;
    }
  }
  __syncthreads();

  // ---- epilogue: transpose to channel-major, nontemporal coalesced stores -
  {
    int px = t & 63;
#pragma unroll
    for (int it = 0; it < 8; ++it) {
      int c = (t >> 6) + it * 4;
      __builtin_nontemporal_store(
          lds_out[px][c],
          &out[((size_t)(b * C_ + c) * H_ + y) * W_ + x0 + px]);
    }
  }
}

extern "C" void kernel_launch(void* const* d_in, const int* in_sizes, int n_in,
                              void* d_out, int out_size, void* d_ws, size_t ws_size,
                              hipStream_t stream) {
  const float* v = (const float*)d_in[0];
  const float* cost_map = (const float*)d_in[1];
  const int* shift_map = (const int*)d_in[2];
  float* out = (float*)d_out;

  unsigned int* vt = (unsigned int*)d_ws;  // B*HW*16 uints = 8.4 MB
  const int grid = B_ * H_ * (W_ / 64);    // 2048 blocks

  transpose_v_kernel<<<B_ * HW_ / 64, 256, 0, stream>>>(v, vt);
  psatt_kernel<<<grid, 256, 0, stream>>>(cost_map, shift_map,
                                         (const __half2*)vt, out);
}

// Round 6
// 44.352 us; speedup vs baseline: 1.2821x; 1.2017x over previous
//
#include <hip/hip_runtime.h>
#include <hip/hip_fp16.h>

#define B_ 2
#define C_ 32
#define H_ 256
#define W_ 256
#define K_ 4
#define HW_ (H_ * W_)

// ---------------------------------------------------------------------------
// Transpose+convert v (B,C,H,W) fp32 -> vt (B,H*W,C) fp16.
// Each pixel's 32 channels = one contiguous 64B segment (one cache line).
// ---------------------------------------------------------------------------
__global__ __launch_bounds__(256) void transpose_v_kernel(
    const float* __restrict__ v, unsigned int* __restrict__ vt) {
  __shared__ float tile[32][65];  // +1 pad: conflict-free transpose reads
  int t = threadIdx.x;
  int pix0 = blockIdx.x * 64;          // global pixel index in [0, B*HW)
  int b = pix0 >> 16;                  // / HW_
  int pixb = pix0 & (HW_ - 1);
  const float* vb = v + (size_t)b * C_ * HW_;
#pragma unroll
  for (int it = 0; it < 8; ++it) {
    int c = (t >> 6) + it * 4;
    int px = t & 63;
    tile[c][px] = __builtin_nontemporal_load(&vb[(size_t)c * HW_ + pixb + px]);
  }
  __syncthreads();
  unsigned int* vtb = vt + (size_t)pix0 * (C_ / 2);
#pragma unroll
  for (int it = 0; it < 4; ++it) {
    int px = (t >> 4) + it * 16;
    int c2 = t & 15;
    float lo = tile[2 * c2][px];
    float hi = tile[2 * c2 + 1][px];
    __half2 h = __floats2half2_rn(lo, hi);
    unsigned int bits;
    __builtin_memcpy(&bits, &h, 4);
    __builtin_nontemporal_store(bits, &vtb[px * 16 + c2]);  // 64B/px coalesced
  }
}

// ---------------------------------------------------------------------------
// Main kernel. One 256-thread block per 64 consecutive x of one row y.
// XCD-batch partition (confirmed R4: FETCH 100->25MB): XCDs 0-3 own batch 0,
// XCDs 4-7 batch 1; each XCD's gather set (vt[b] = 4 MiB) fits its L2.
// Phase 2: each 4-lane quad owns one pixel; lane gathers 16B (8 channels)
// via dwordx4 -> 4x fewer vmem instructions. Taps processed in chunks of 18
// held entirely in VGPRs (launch_bounds(256,3): cap 168) for deep MLP over
// ~300cy L2-hit latency (R5 lesson: cap 128 forced serialization).
// ---------------------------------------------------------------------------
__global__ __launch_bounds__(256, 3) void psatt_kernel(
    const float* __restrict__ cost_map, const int* __restrict__ shift_map,
    const unsigned int* __restrict__ vt, float* __restrict__ out) {
  __shared__ float2 lds_eo[36][64];  // (e, off-bits); [m][px]: conflict-free
                                     // both on ph1 write and ph2 b64 read
  __shared__ float lds_part[64][4];
  __shared__ float lds_inv[64];
  __shared__ float lds_out[64][33];  // stride 33: conflict-free epilogue

  int t = threadIdx.x;
  // XCD-aware decomposition (empirical round-robin: XCD = blockIdx % 8).
  int bid = blockIdx.x;           // 0..2047
  int xcd = bid & 7;
  int slot = bid >> 3;            // 0..255
  int b = xcd >> 2;               // XCDs 0-3 -> batch 0, 4-7 -> batch 1
  int workid = ((xcd & 3) << 8) + slot;  // 0..1023; 64 contiguous rows/XCD
  int y = workid >> 2;
  int x0 = (workid & 3) << 6;

  // ---- phase 1: weights + offsets (plain loads: halo rows L2-reused) ------
  {
    int k = t >> 6;   // one wave per k-plane
    int px = t & 63;
    int x = x0 + px;
    const float* cm = cost_map + (size_t)(b * K_ + k) * HW_;
    const int* s0 = shift_map + (size_t)((b * 2 + 0) * K_ + k) * HW_;
    const int* s1 = shift_map + (size_t)((b * 2 + 1) * K_ + k) * HW_;
    float psum = 0.f;
#pragma unroll
    for (int di = 0; di < 3; ++di) {
      int ny = y + di - 1;
      bool yin = (unsigned)ny < (unsigned)H_;
#pragma unroll
      for (int dj = 0; dj < 3; ++dj) {
        int nx = x + dj - 1;
        bool inb = yin && ((unsigned)nx < (unsigned)W_);
        int nidx = ny * W_ + nx;
        float cost;
        int si, sj;
        if (inb) {
          cost = cm[nidx];
          si = s0[nidx] + (1 - di);
          sj = s1[nidx] + (1 - dj);
        } else {
          cost = 10.0f;     // pad value of cost_map
          si = 11 - di;     // pad value 10 + (1 - di)
          sj = 11 - dj;
        }
        float e = __expf(-cost);  // T = 1; no max-sub needed (range safe)
        int ii = min(max(si, 0), H_ - 1);
        int jj = min(max(sj, 0), W_ - 1);
        int m = k * 9 + di * 3 + dj;
        lds_eo[m][px] = make_float2(e, __int_as_float(ii * W_ + jj));
        psum += e;
      }
    }
    lds_part[px][k] = psum;
  }
  __syncthreads();
  if (t < 64) {
    lds_inv[t] =
        1.0f / (lds_part[t][0] + lds_part[t][1] + lds_part[t][2] + lds_part[t][3]);
  }
  __syncthreads();

  // ---- phase 2: weighted gather-sum, dwordx4, 18-tap register batches -----
  {
    int q = t & 3;      // 16B quad within pixel: channels 8q..8q+7
    int px = t >> 2;    // 0..63 (each wave covers 16 pixels)
    const uint4* vbase = (const uint4*)vt + (size_t)b * HW_ * 4 + q;
    float acc[8] = {0.f, 0.f, 0.f, 0.f, 0.f, 0.f, 0.f, 0.f};
#pragma unroll
    for (int half = 0; half < 2; ++half) {
      uint4 hv[18];
      float ew[18];
#pragma unroll
      for (int m = 0; m < 18; ++m) {
        float2 eo = lds_eo[half * 18 + m][px];  // one ds_read_b64
        ew[m] = eo.x;
        int off = __float_as_int(eo.y);
        hv[m] = vbase[(size_t)off << 2];        // global_load_dwordx4
      }
#pragma unroll
      for (int m = 0; m < 18; ++m) {
        float e = ew[m];
        __half2 h0, h1, h2, h3;
        __builtin_memcpy(&h0, &hv[m].x, 4);
        __builtin_memcpy(&h1, &hv[m].y, 4);
        __builtin_memcpy(&h2, &hv[m].z, 4);
        __builtin_memcpy(&h3, &hv[m].w, 4);
        float2 f0 = __half22float2(h0);
        float2 f1 = __half22float2(h1);
        float2 f2 = __half22float2(h2);
        float2 f3 = __half22float2(h3);
        acc[0] += e * f0.x; acc[1] += e * f0.y;
        acc[2] += e * f1.x; acc[3] += e * f1.y;
        acc[4] += e * f2.x; acc[5] += e * f2.y;
        acc[6] += e * f3.x; acc[7] += e * f3.y;
      }
    }
    float inv = lds_inv[px];
#pragma unroll
    for (int j = 0; j < 8; ++j) {
      lds_out[px][8 * q + j] = acc[j] * inv;
    }
  }
  __syncthreads();

  // ---- epilogue: transpose to channel-major, nontemporal coalesced stores -
  {
    int px = t & 63;
#pragma unroll
    for (int it = 0; it < 8; ++it) {
      int c = (t >> 6) + it * 4;
      __builtin_nontemporal_store(
          lds_out[px][c],
          &out[((size_t)(b * C_ + c) * H_ + y) * W_ + x0 + px]);
    }
  }
}

extern "C" void kernel_launch(void* const* d_in, const int* in_sizes, int n_in,
                              void* d_out, int out_size, void* d_ws, size_t ws_size,
                              hipStream_t stream) {
  const float* v = (const float*)d_in[0];
  const float* cost_map = (const float*)d_in[1];
  const int* shift_map = (const int*)d_in[2];
  float* out = (float*)d_out;

  unsigned int* vt = (unsigned int*)d_ws;  // B*HW*16 uints = 8.4 MB
  const int grid = B_ * H_ * (W_ / 64);    // 2048 blocks

  transpose_v_kernel<<<B_ * HW_ / 64, 256, 0, stream>>>(v, vt);
  psatt_kernel<<<grid, 256, 0, stream>>>(cost_map, shift_map, vt, out);
}